// Round 7
// baseline (3387.531 us; speedup 1.0000x reference)
//
#include <hip/hip_runtime.h>

typedef _Float16 f16;
using f16x8 = __attribute__((ext_vector_type(8))) _Float16;
using f32x4 = __attribute__((ext_vector_type(4))) float;

#define H 256
#define NM 2048

// async 16B global -> LDS (wave-uniform LDS base + lane*16)
__device__ __forceinline__ void gload_lds16(const f16* g, f16* lds)
{
    __builtin_amdgcn_global_load_lds(
        (const __attribute__((address_space(1))) void*)g,
        (__attribute__((address_space(3))) void*)lds, 16, 0, 0);
}

// ---------------------------------------------------------------------------
// C[M,256] = relu( A1[M,K1r] @ W1[256,128]^T
//                + gather10(src2, idx2)[M,K2] @ W2[256,K2]^T + bias )
// A1 f32 (optional, K1r<=128, W1 K-padded to 128). src2 f16 (optional):
// idx2 != null -> A2 row i = sum_{j<10} src2[idx2[i][j],:] (computed in
// staging, ONE sweep per 128-k slab); else direct rows (M mult of 64).
// Tile 64x256, 4 waves (64x64 each), BK=64 per barrier, f32 MFMA accum.
// LDS: As[64][128] slab + Bs[256][64]; 16B-chunk XOR swizzle (chunk ^= row&7)
// on write/source + matching fragment reads (verified conflict-free, r5/r6).
__global__ __launch_bounds__(256) void gemm_fused(
    const float* __restrict__ A1, int lda1, int K1r,
    const f16*  __restrict__ W1,
    const f16*  __restrict__ src2, const int* __restrict__ idx2, int lda2,
    const f16*  __restrict__ W2, int K2,
    const float* __restrict__ bias, f16* __restrict__ C, int M)
{
    __shared__ f16 As[64][128];     // one 128-k slab
    __shared__ f16 Bs[256][64];     // one 64-k chunk of W

    const int bm = blockIdx.x * 64;
    const int tid  = threadIdx.x;
    const int wave = tid >> 6, lane = tid & 63;
    const int lrow = lane & 15;
    const int kg   = lane >> 4;
    const int swz  = lrow & 7;

    // Bs gload lane decomposition: 64 lanes x 16B = 8 rows x 8 chunks
    const int glr = lane >> 3;
    const int glc = lane & 7;
    const int gsc = glc ^ glr;          // swizzled source chunk

    // A staging: 4 threads per row, 32 halfs (4 chunks) each
    const int arow = tid >> 2;
    const int aq   = tid & 3;
    const int ars  = arow & 7;

    f32x4 acc[4][4];
    #pragma unroll
    for (int m = 0; m < 4; ++m)
        #pragma unroll
        for (int n = 0; n < 4; ++n)
            acc[m][n] = (f32x4){0.f, 0.f, 0.f, 0.f};

    // two MFMA k-steps (32 k each) reading As slab chunks (kw0..kw0+1)
    auto mfma_half = [&](int kw0) {
        #pragma unroll
        for (int ks = 0; ks < 2; ++ks) {
            f16x8 af[4], bf[4];
            const int ca = (((kw0 + ks) * 4 + kg) ^ swz) * 8;   // As: 16 chunks
            const int cb = ((ks * 4 + kg) ^ swz) * 8;           // Bs: 8 chunks
            #pragma unroll
            for (int m = 0; m < 4; ++m)
                af[m] = *(const f16x8*)&As[m * 16 + lrow][ca];
            #pragma unroll
            for (int n = 0; n < 4; ++n)
                bf[n] = *(const f16x8*)&Bs[wave * 64 + n * 16 + lrow][cb];
            #pragma unroll
            for (int m = 0; m < 4; ++m)
                #pragma unroll
                for (int n = 0; n < 4; ++n)
                    acc[m][n] = __builtin_amdgcn_mfma_f32_16x16x32_f16(af[m], bf[n], acc[m][n], 0, 0, 0);
        }
    };

    auto stageB = [&](const f16* W, int ldw, int k0) {
        #pragma unroll
        for (int q = 0; q < 8; ++q)
            gload_lds16(W + (size_t)(wave * 64 + q * 8 + glr) * ldw + k0 + gsc * 8,
                        &Bs[wave * 64 + q * 8][0]);
    };

    // ---- pass 0: f32 A1 (reg-staged with bounds), one 128-k slab ----
    if (A1 != nullptr) {
        {
            int gr = bm + arow;
            const float* srcp = A1 + (size_t)gr * lda1 + aq * 32;
            f16 tmp[32];
            #pragma unroll
            for (int i = 0; i < 32; i += 2) {
                float x = 0.f, y = 0.f;
                int gk = aq * 32 + i;
                if (gr < M) {
                    if (gk + 1 < K1r) { float2 v = *(const float2*)(srcp + i); x = v.x; y = v.y; }
                    else if (gk < K1r) { x = srcp[i]; }
                }
                tmp[i] = (f16)x; tmp[i + 1] = (f16)y;
            }
            #pragma unroll
            for (int t = 0; t < 4; ++t)
                *(float4*)&As[arow][((aq * 4 + t) ^ ars) * 8] = *(float4*)&tmp[t * 8];
        }
        #pragma unroll
        for (int h = 0; h < 2; ++h) {
            stageB(W1, 128, h * 64);
            __syncthreads();
            mfma_half(h * 2);
            __syncthreads();
        }
    }

    // ---- pass 1: gathered (or direct) f16 A2, 128-k slabs ----
    if (src2 != nullptr) {
        int ip[10];
        const bool rowok = (bm + arow) < M;
        if (idx2 != nullptr && rowok) {
            const int* ipp = idx2 + (size_t)(bm + arow) * 10;
            #pragma unroll
            for (int j = 0; j < 10; ++j) ip[j] = ipp[j];
        }
        for (int ks0 = 0; ks0 < K2; ks0 += 128) {
            if (idx2 != nullptr) {
                float s[32] = {};
                if (rowok) {
                    #pragma unroll
                    for (int j = 0; j < 10; ++j) {
                        const f16* p = src2 + (size_t)ip[j] * lda2 + ks0 + aq * 32;
                        #pragma unroll
                        for (int t = 0; t < 4; ++t) {
                            float4 v = *(const float4*)(p + t * 8);
                            const f16* pb = (const f16*)&v;
                            #pragma unroll
                            for (int e = 0; e < 8; ++e) s[t * 8 + e] += (float)pb[e];
                        }
                    }
                }
                #pragma unroll
                for (int t = 0; t < 4; ++t) {
                    f16 tmp[8];
                    #pragma unroll
                    for (int e = 0; e < 8; ++e) tmp[e] = (f16)s[t * 8 + e];
                    *(float4*)&As[arow][((aq * 4 + t) ^ ars) * 8] = *(float4*)tmp;
                }
            } else {
                // direct rows: 4 gloads/wave, each covers 4 rows x 16 chunks
                #pragma unroll
                for (int q = 0; q < 4; ++q) {
                    int row = wave * 16 + q * 4 + (lane >> 4);
                    int chunk = (lane & 15) ^ (row & 7);
                    gload_lds16(src2 + (size_t)(bm + row) * lda2 + ks0 + chunk * 8,
                                &As[wave * 16 + q * 4][0]);
                }
            }
            #pragma unroll
            for (int h = 0; h < 2; ++h) {
                stageB(W2, K2, ks0 + h * 64);
                __syncthreads();
                mfma_half(h * 2);
                __syncthreads();
            }
        }
    }

    // epilogue: C/D layout col=lane&15, row=kg*4+reg (validated rounds 3-6)
    #pragma unroll
    for (int n = 0; n < 4; ++n) {
        int gc = wave * 64 + n * 16 + lrow;
        float bv = bias ? bias[gc] : 0.f;
        #pragma unroll
        for (int m = 0; m < 4; ++m) {
            #pragma unroll
            for (int r = 0; r < 4; ++r) {
                int gr = bm + m * 16 + kg * 4 + r;
                if (gr < M) C[(size_t)gr * H + gc] = (f16)fmaxf(acc[m][n][r] + bv, 0.f);
            }
        }
    }
}

// ---------------------------------------------------------------------------
// weight pre-convert: dst[n][k] = k < kvalid ? src[n*lds_+koff+k] : 0   (f16)
__global__ __launch_bounds__(256) void convert_w(
    const float* __restrict__ src, int lds_, int koff, int kvalid,
    f16* __restrict__ dst, int Kd)
{
    int n = blockIdx.x;
    for (int k = threadIdx.x; k < Kd; k += 256) {
        float v = (k < kvalid) ? src[(size_t)n * lds_ + koff + k] : 0.f;
        dst[(size_t)n * Kd + k] = (f16)v;
    }
}

__global__ __launch_bounds__(256) void segsum(
    const f16* __restrict__ atom_h, const int* __restrict__ mol_idx,
    float* __restrict__ mol_h, int n_atoms)
{
    int m = blockIdx.x;
    int lo = 0, hi = n_atoms;
    while (lo < hi) { int mid = (lo + hi) >> 1; if (mol_idx[mid] < m) lo = mid + 1; else hi = mid; }
    int start = lo;
    hi = n_atoms;
    while (lo < hi) { int mid = (lo + hi) >> 1; if (mol_idx[mid] < m + 1) lo = mid + 1; else hi = mid; }
    int end = lo;
    int c = threadIdx.x;
    float s = 0.f;
    for (int a = start; a < end; ++a) s += (float)atom_h[(size_t)a * H + c];
    mol_h[(size_t)m * H + c] = s;
}

__global__ __launch_bounds__(256) void diff_kernel(
    const float* __restrict__ a, const float* __restrict__ b,
    f16* __restrict__ c, int n)
{
    int i = blockIdx.x * 256 + threadIdx.x;
    if (i < n) c[i] = (f16)(a[i] - b[i]);
}

__global__ __launch_bounds__(256) void final_dot(
    const f16* __restrict__ rxn, const float* __restrict__ Wro,
    const float* __restrict__ bro, float* __restrict__ out)
{
    int m = blockIdx.x;
    int t = threadIdx.x;
    float v = (float)rxn[(size_t)m * H + t] * Wro[t];
    #pragma unroll
    for (int off = 32; off; off >>= 1) v += __shfl_down(v, off, 64);
    __shared__ float red[4];
    if ((t & 63) == 0) red[t >> 6] = v;
    __syncthreads();
    if (t == 0) out[m] = red[0] + red[1] + red[2] + red[3] + bro[0];
}

// ---------------------------------------------------------------------------
static void run_graph(const float* fatoms, const float* fbonds, const int* agraph,
                      const int* bgraph, const int* mol_idx,
                      const f16* Wi16, const f16* Wh16, const f16* Wo1, const f16* Wo2,
                      const float* bo,
                      f16* bufA, f16* bufB, float* molh,
                      int n_atoms, int n_bonds, hipStream_t stream)
{
    dim3 gb((n_bonds + 63) / 64);
    dim3 ga((n_atoms + 63) / 64);

    // msg0 = relu(fbonds @ Wi^T)
    gemm_fused<<<gb, 256, 0, stream>>>(fbonds, 88, 88, Wi16,
                                       (const f16*)nullptr, (const int*)nullptr, 0,
                                       (const f16*)nullptr, 0,
                                       (const float*)nullptr, bufA, n_bonds);
    f16* cur = bufA; f16* nxt = bufB;
    for (int it = 0; it < 3; ++it) {
        // msg = relu(fbonds@Wi^T + gather10(msg, bgraph)@Wh^T)   (fused)
        gemm_fused<<<gb, 256, 0, stream>>>(fbonds, 88, 88, Wi16,
                                           cur, bgraph, H, Wh16, H,
                                           (const float*)nullptr, nxt, n_bonds);
        f16* t = cur; cur = nxt; nxt = t;
    }
    // atom_h = relu(fatoms@Wo[:,:82]^T + gather10(msg, agraph)@Wo[:,82:]^T + bo)
    gemm_fused<<<ga, 256, 0, stream>>>(fatoms, 82, 82, Wo1,
                                       cur, agraph, H, Wo2, H,
                                       bo, nxt, n_atoms);
    segsum<<<NM, 256, 0, stream>>>(nxt, mol_idx, molh, n_atoms);
}

extern "C" void kernel_launch(void* const* d_in, const int* in_sizes, int n_in,
                              void* d_out, int out_size, void* d_ws, size_t ws_size,
                              hipStream_t stream)
{
    const float* fatoms_src = (const float*)d_in[0];
    const float* fbonds_src = (const float*)d_in[1];
    const int*   agraph_src = (const int*)d_in[2];
    const int*   bgraph_src = (const int*)d_in[3];
    const int*   mol_idx_src= (const int*)d_in[4];
    const float* fatoms_tgt = (const float*)d_in[5];
    const float* fbonds_tgt = (const float*)d_in[6];
    const int*   agraph_tgt = (const int*)d_in[7];
    const int*   bgraph_tgt = (const int*)d_in[8];
    const int*   mol_idx_tgt= (const int*)d_in[9];
    const float* Wi_s = (const float*)d_in[10];
    const float* Wh_s = (const float*)d_in[11];
    const float* Wo_s = (const float*)d_in[12];
    const float* bo_s = (const float*)d_in[13];
    const float* Wi_t = (const float*)d_in[14];
    const float* Wh_t = (const float*)d_in[15];
    const float* Wo_t = (const float*)d_in[16];
    const float* bo_t = (const float*)d_in[17];
    const float* Wrh  = (const float*)d_in[18];
    const float* brh  = (const float*)d_in[19];
    const float* Wro  = (const float*)d_in[20];
    const float* bro  = (const float*)d_in[21];

    const int n_atoms = in_sizes[0] / 82;
    const int n_bonds = in_sizes[1] / 88;

    // ---- workspace layout (~212 MB, same proven footprint) ----
    char* ws = (char*)d_ws;
    size_t off = 0;
    auto alloc = [&](size_t bytes) { size_t o = off; off = (off + bytes + 255) & ~(size_t)255; return o; };
    f16*   bufA = (f16*)(ws + alloc((size_t)n_bonds * H * 2));
    f16*   bufB = (f16*)(ws + alloc((size_t)n_bonds * H * 2));
    float* molS = (float*)(ws + alloc((size_t)NM * H * 4));
    float* molT = (float*)(ws + alloc((size_t)NM * H * 4));
    f16*   dbuf = (f16*)(ws + alloc((size_t)NM * H * 2));
    f16*   rxn  = (f16*)(ws + alloc((size_t)NM * H * 2));
    f16* Wi16_s = (f16*)(ws + alloc(256 * 128 * 2));
    f16* Wh16_s = (f16*)(ws + alloc(256 * 256 * 2));
    f16* Wo1_s  = (f16*)(ws + alloc(256 * 128 * 2));
    f16* Wo2_s  = (f16*)(ws + alloc(256 * 256 * 2));
    f16* Wi16_t = (f16*)(ws + alloc(256 * 128 * 2));
    f16* Wh16_t = (f16*)(ws + alloc(256 * 256 * 2));
    f16* Wo1_t  = (f16*)(ws + alloc(256 * 128 * 2));
    f16* Wo2_t  = (f16*)(ws + alloc(256 * 256 * 2));
    f16* Wrh16  = (f16*)(ws + alloc(256 * 256 * 2));

    // ---- pre-convert weights to K-padded f16 (tiny) ----
    convert_w<<<256, 256, 0, stream>>>(Wi_s,  88,  0,  88, Wi16_s, 128);
    convert_w<<<256, 256, 0, stream>>>(Wh_s, 256,  0, 256, Wh16_s, 256);
    convert_w<<<256, 256, 0, stream>>>(Wo_s, 338,  0,  82, Wo1_s, 128);
    convert_w<<<256, 256, 0, stream>>>(Wo_s, 338, 82, 256, Wo2_s, 256);
    convert_w<<<256, 256, 0, stream>>>(Wi_t,  88,  0,  88, Wi16_t, 128);
    convert_w<<<256, 256, 0, stream>>>(Wh_t, 256,  0, 256, Wh16_t, 256);
    convert_w<<<256, 256, 0, stream>>>(Wo_t, 338,  0,  82, Wo1_t, 128);
    convert_w<<<256, 256, 0, stream>>>(Wo_t, 338, 82, 256, Wo2_t, 256);
    convert_w<<<256, 256, 0, stream>>>(Wrh, 256,  0, 256, Wrh16, 256);

    run_graph(fatoms_src, fbonds_src, agraph_src, bgraph_src, mol_idx_src,
              Wi16_s, Wh16_s, Wo1_s, Wo2_s, bo_s,
              bufA, bufB, molS, n_atoms, n_bonds, stream);
    run_graph(fatoms_tgt, fbonds_tgt, agraph_tgt, bgraph_tgt, mol_idx_tgt,
              Wi16_t, Wh16_t, Wo1_t, Wo2_t, bo_t,
              bufA, bufB, molT, n_atoms, n_bonds, stream);

    diff_kernel<<<(NM * H + 255) / 256, 256, 0, stream>>>(molT, molS, dbuf, NM * H);
    // rxn_h = relu(diff @ Wrh^T + brh)   (direct-A2 mode, M=2048 = 32*64)
    gemm_fused<<<NM / 64, 256, 0, stream>>>((const float*)nullptr, 0, 0, (const f16*)nullptr,
                                            dbuf, (const int*)nullptr, H, Wrh16, H,
                                            brh, rxn, NM);
    final_dot<<<NM, 256, 0, stream>>>(rxn, Wro, bro, (float*)d_out);
}

// Round 8
// 2667.434 us; speedup vs baseline: 1.2700x; 1.2700x over previous
//
#include <hip/hip_runtime.h>

typedef _Float16 f16;
using f16x8 = __attribute__((ext_vector_type(8))) _Float16;
using f32x4 = __attribute__((ext_vector_type(4))) float;

#define H 256
#define NM 2048

template<int N> struct Int { static constexpr int v = N; };

// async 16B global -> LDS (wave-uniform LDS base + lane*16)
__device__ __forceinline__ void gload_lds16(const f16* g, f16* lds)
{
    __builtin_amdgcn_global_load_lds(
        (const __attribute__((address_space(1))) void*)g,
        (__attribute__((address_space(3))) void*)lds, 16, 0, 0);
}

// ---------------------------------------------------------------------------
// C[M,256] = relu( A1[M,K1r] @ W1[256,128]^T
//                + gather10(src2, idx2)[M,256] @ W2[256,256]^T + bias )
// Block = 64 rows; wave w owns rows [bm+16w, bm+16w+16) x all 256 cols.
// A-operand lives ONLY in registers: lane (kg,lrow) holds row (bm+16w+lrow),
// chunks c=4t+kg (t=0..7) as af[8] f16x8. Gather sums 10 neighbor rows
// directly into af via packed f16 adds (2 interleaved accumulators).
// B staged in LDS Bs[256][64] per 64-k window via global_load_lds with the
// proven chunk^row XOR swizzle (r5/r6: SQ_LDS_BANK_CONFLICT == 0).
__global__ __launch_bounds__(256, 3) void gemm_fused(
    const float* __restrict__ A1, int lda1, int K1r,
    const f16*  __restrict__ W1,
    const f16*  __restrict__ src2, const int* __restrict__ idx2,
    const f16*  __restrict__ W2,
    const float* __restrict__ bias, f16* __restrict__ C, int M)
{
    __shared__ f16 Bs[256][64];

    const int bm   = blockIdx.x * 64;
    const int tid  = threadIdx.x;
    const int wave = tid >> 6, lane = tid & 63;
    const int lrow = lane & 15;
    const int kg   = lane >> 4;
    const int swz  = lrow & 7;

    // Bs gload lane decomposition: 64 lanes x 16B = 8 rows x 8 chunks
    const int glr = lane >> 3;
    const int gsc = (lane & 7) ^ glr;   // swizzled source chunk

    const int  myrow = bm + wave * 16 + lrow;
    const bool rowok = myrow < M;

    f32x4 acc[16];
    #pragma unroll
    for (int n = 0; n < 16; ++n) acc[n] = (f32x4){0.f, 0.f, 0.f, 0.f};

    f16x8 af[8];

    auto stageB = [&](const f16* W, int ldw, int k0) {
        #pragma unroll
        for (int q = 0; q < 8; ++q)
            gload_lds16(W + (size_t)(wave * 64 + q * 8 + glr) * ldw + k0 + gsc * 8,
                        &Bs[wave * 64 + q * 8][0]);
    };

    // nwin 64-k windows against weight W (ldw = nwin*64); af[w*2+ks] = A chunks
    auto windows = [&](auto NW, const f16* W, int ldw) {
        constexpr int nw = decltype(NW)::v;
        #pragma unroll
        for (int w = 0; w < nw; ++w) {
            stageB(W, ldw, w * 64);
            __syncthreads();
            #pragma unroll
            for (int ks = 0; ks < 2; ++ks) {
                const int cb = ((ks * 4 + kg) ^ swz) * 8;
                const f16x8 a = af[w * 2 + ks];
                #pragma unroll
                for (int n = 0; n < 16; ++n) {
                    f16x8 b = *(const f16x8*)&Bs[n * 16 + lrow][cb];
                    acc[n] = __builtin_amdgcn_mfma_f32_16x16x32_f16(a, b, acc[n], 0, 0, 0);
                }
            }
            __syncthreads();
        }
    };

    // ---- pass 0: A1 f32, K padded to 128 (chunks c=4t+kg, t=0..3) ----
    if (A1 != nullptr) {
        #pragma unroll
        for (int t = 0; t < 4; ++t) {
            const int k0 = (4 * t + kg) * 8;
            const float* sp = A1 + (size_t)myrow * lda1 + k0;
            f16 tmp[8];
            #pragma unroll
            for (int i = 0; i < 8; i += 2) {
                float x = 0.f, y = 0.f;
                if (rowok) {
                    if (k0 + i + 1 < K1r) { float2 v = *(const float2*)(sp + i); x = v.x; y = v.y; }
                    else if (k0 + i < K1r) { x = sp[i]; }
                }
                tmp[i] = (f16)x; tmp[i + 1] = (f16)y;
            }
            af[t] = *(const f16x8*)tmp;
        }
        windows(Int<2>{}, W1, 128);
    }

    // ---- pass 1: gathered (or direct) f16 A2, K = 256 ----
    if (src2 != nullptr) {
        if (idx2 != nullptr) {
            int ip[10];
            if (rowok) {
                const int* p = idx2 + (size_t)myrow * 10;
                #pragma unroll
                for (int j = 0; j < 10; ++j) ip[j] = p[j];
            } else {
                #pragma unroll
                for (int j = 0; j < 10; ++j) ip[j] = 0;
            }
            const f16* base = src2 + kg * 8;
            #pragma unroll
            for (int t = 0; t < 8; ++t) {
                f16x8 vA = *(const f16x8*)(base + (size_t)ip[0] * H + t * 32);
                f16x8 vB = *(const f16x8*)(base + (size_t)ip[1] * H + t * 32);
                #pragma unroll
                for (int j = 2; j < 10; j += 2) {
                    f16x8 u0 = *(const f16x8*)(base + (size_t)ip[j]     * H + t * 32);
                    f16x8 u1 = *(const f16x8*)(base + (size_t)ip[j + 1] * H + t * 32);
                    vA = vA + u0;
                    vB = vB + u1;
                }
                f16x8 s = vA + vB;
                if (!rowok) {
                    #pragma unroll
                    for (int e = 0; e < 8; ++e) s[e] = (f16)0.f;
                }
                af[t] = s;
            }
        } else {
            // direct rows
            #pragma unroll
            for (int t = 0; t < 8; ++t) {
                if (rowok)
                    af[t] = *(const f16x8*)(src2 + (size_t)myrow * H + kg * 8 + t * 32);
                else {
                    #pragma unroll
                    for (int e = 0; e < 8; ++e) af[t][e] = (f16)0.f;
                }
            }
        }
        windows(Int<4>{}, W2, 256);
    }

    // epilogue: C/D layout col=lane&15, row=kg*4+reg (validated rounds 3-7)
    #pragma unroll
    for (int n = 0; n < 16; ++n) {
        const int gc = n * 16 + lrow;
        const float bv = bias ? bias[gc] : 0.f;
        #pragma unroll
        for (int r = 0; r < 4; ++r) {
            const int gr = bm + wave * 16 + kg * 4 + r;
            if (gr < M) C[(size_t)gr * H + gc] = (f16)fmaxf(acc[n][r] + bv, 0.f);
        }
    }
}

// ---------------------------------------------------------------------------
// weight pre-convert: dst[n][k] = k < kvalid ? src[n*lds_+koff+k] : 0   (f16)
__global__ __launch_bounds__(256) void convert_w(
    const float* __restrict__ src, int lds_, int koff, int kvalid,
    f16* __restrict__ dst, int Kd)
{
    int n = blockIdx.x;
    for (int k = threadIdx.x; k < Kd; k += 256) {
        float v = (k < kvalid) ? src[(size_t)n * lds_ + koff + k] : 0.f;
        dst[(size_t)n * Kd + k] = (f16)v;
    }
}

__global__ __launch_bounds__(256) void segsum(
    const f16* __restrict__ atom_h, const int* __restrict__ mol_idx,
    float* __restrict__ mol_h, int n_atoms)
{
    int m = blockIdx.x;
    int lo = 0, hi = n_atoms;
    while (lo < hi) { int mid = (lo + hi) >> 1; if (mol_idx[mid] < m) lo = mid + 1; else hi = mid; }
    int start = lo;
    hi = n_atoms;
    while (lo < hi) { int mid = (lo + hi) >> 1; if (mol_idx[mid] < m + 1) lo = mid + 1; else hi = mid; }
    int end = lo;
    int c = threadIdx.x;
    float s = 0.f;
    for (int a = start; a < end; ++a) s += (float)atom_h[(size_t)a * H + c];
    mol_h[(size_t)m * H + c] = s;
}

__global__ __launch_bounds__(256) void diff_kernel(
    const float* __restrict__ a, const float* __restrict__ b,
    f16* __restrict__ c, int n)
{
    int i = blockIdx.x * 256 + threadIdx.x;
    if (i < n) c[i] = (f16)(a[i] - b[i]);
}

__global__ __launch_bounds__(256) void final_dot(
    const f16* __restrict__ rxn, const float* __restrict__ Wro,
    const float* __restrict__ bro, float* __restrict__ out)
{
    int m = blockIdx.x;
    int t = threadIdx.x;
    float v = (float)rxn[(size_t)m * H + t] * Wro[t];
    #pragma unroll
    for (int off = 32; off; off >>= 1) v += __shfl_down(v, off, 64);
    __shared__ float red[4];
    if ((t & 63) == 0) red[t >> 6] = v;
    __syncthreads();
    if (t == 0) out[m] = red[0] + red[1] + red[2] + red[3] + bro[0];
}

// ---------------------------------------------------------------------------
static void run_graph(const float* fatoms, const float* fbonds, const int* agraph,
                      const int* bgraph, const int* mol_idx,
                      const f16* Wi16, const f16* Wh16, const f16* Wo1, const f16* Wo2,
                      const float* bo,
                      f16* bufA, f16* bufB, float* molh,
                      int n_atoms, int n_bonds, hipStream_t stream)
{
    dim3 gb((n_bonds + 63) / 64);
    dim3 ga((n_atoms + 63) / 64);

    // msg0 = relu(fbonds @ Wi^T)
    gemm_fused<<<gb, 256, 0, stream>>>(fbonds, 88, 88, Wi16,
                                       (const f16*)nullptr, (const int*)nullptr,
                                       (const f16*)nullptr,
                                       (const float*)nullptr, bufA, n_bonds);
    f16* cur = bufA; f16* nxt = bufB;
    for (int it = 0; it < 3; ++it) {
        // msg = relu(fbonds@Wi^T + gather10(msg, bgraph)@Wh^T)   (fused)
        gemm_fused<<<gb, 256, 0, stream>>>(fbonds, 88, 88, Wi16,
                                           cur, bgraph, Wh16,
                                           (const float*)nullptr, nxt, n_bonds);
        f16* t = cur; cur = nxt; nxt = t;
    }
    // atom_h = relu(fatoms@Wo[:,:82]^T + gather10(msg, agraph)@Wo[:,82:]^T + bo)
    gemm_fused<<<ga, 256, 0, stream>>>(fatoms, 82, 82, Wo1,
                                       cur, agraph, Wo2,
                                       bo, nxt, n_atoms);
    segsum<<<NM, 256, 0, stream>>>(nxt, mol_idx, molh, n_atoms);
}

extern "C" void kernel_launch(void* const* d_in, const int* in_sizes, int n_in,
                              void* d_out, int out_size, void* d_ws, size_t ws_size,
                              hipStream_t stream)
{
    const float* fatoms_src = (const float*)d_in[0];
    const float* fbonds_src = (const float*)d_in[1];
    const int*   agraph_src = (const int*)d_in[2];
    const int*   bgraph_src = (const int*)d_in[3];
    const int*   mol_idx_src= (const int*)d_in[4];
    const float* fatoms_tgt = (const float*)d_in[5];
    const float* fbonds_tgt = (const float*)d_in[6];
    const int*   agraph_tgt = (const int*)d_in[7];
    const int*   bgraph_tgt = (const int*)d_in[8];
    const int*   mol_idx_tgt= (const int*)d_in[9];
    const float* Wi_s = (const float*)d_in[10];
    const float* Wh_s = (const float*)d_in[11];
    const float* Wo_s = (const float*)d_in[12];
    const float* bo_s = (const float*)d_in[13];
    const float* Wi_t = (const float*)d_in[14];
    const float* Wh_t = (const float*)d_in[15];
    const float* Wo_t = (const float*)d_in[16];
    const float* bo_t = (const float*)d_in[17];
    const float* Wrh  = (const float*)d_in[18];
    const float* brh  = (const float*)d_in[19];
    const float* Wro  = (const float*)d_in[20];
    const float* bro  = (const float*)d_in[21];

    const int n_atoms = in_sizes[0] / 82;
    const int n_bonds = in_sizes[1] / 88;

    // ---- workspace layout (~212 MB, same proven footprint) ----
    char* ws = (char*)d_ws;
    size_t off = 0;
    auto alloc = [&](size_t bytes) { size_t o = off; off = (off + bytes + 255) & ~(size_t)255; return o; };
    f16*   bufA = (f16*)(ws + alloc((size_t)n_bonds * H * 2));
    f16*   bufB = (f16*)(ws + alloc((size_t)n_bonds * H * 2));
    float* molS = (float*)(ws + alloc((size_t)NM * H * 4));
    float* molT = (float*)(ws + alloc((size_t)NM * H * 4));
    f16*   dbuf = (f16*)(ws + alloc((size_t)NM * H * 2));
    f16*   rxn  = (f16*)(ws + alloc((size_t)NM * H * 2));
    f16* Wi16_s = (f16*)(ws + alloc(256 * 128 * 2));
    f16* Wh16_s = (f16*)(ws + alloc(256 * 256 * 2));
    f16* Wo1_s  = (f16*)(ws + alloc(256 * 128 * 2));
    f16* Wo2_s  = (f16*)(ws + alloc(256 * 256 * 2));
    f16* Wi16_t = (f16*)(ws + alloc(256 * 128 * 2));
    f16* Wh16_t = (f16*)(ws + alloc(256 * 256 * 2));
    f16* Wo1_t  = (f16*)(ws + alloc(256 * 128 * 2));
    f16* Wo2_t  = (f16*)(ws + alloc(256 * 256 * 2));
    f16* Wrh16  = (f16*)(ws + alloc(256 * 256 * 2));

    // ---- pre-convert weights to K-padded f16 (tiny) ----
    convert_w<<<256, 256, 0, stream>>>(Wi_s,  88,  0,  88, Wi16_s, 128);
    convert_w<<<256, 256, 0, stream>>>(Wh_s, 256,  0, 256, Wh16_s, 256);
    convert_w<<<256, 256, 0, stream>>>(Wo_s, 338,  0,  82, Wo1_s, 128);
    convert_w<<<256, 256, 0, stream>>>(Wo_s, 338, 82, 256, Wo2_s, 256);
    convert_w<<<256, 256, 0, stream>>>(Wi_t,  88,  0,  88, Wi16_t, 128);
    convert_w<<<256, 256, 0, stream>>>(Wh_t, 256,  0, 256, Wh16_t, 256);
    convert_w<<<256, 256, 0, stream>>>(Wo_t, 338,  0,  82, Wo1_t, 128);
    convert_w<<<256, 256, 0, stream>>>(Wo_t, 338, 82, 256, Wo2_t, 256);
    convert_w<<<256, 256, 0, stream>>>(Wrh, 256,  0, 256, Wrh16, 256);

    run_graph(fatoms_src, fbonds_src, agraph_src, bgraph_src, mol_idx_src,
              Wi16_s, Wh16_s, Wo1_s, Wo2_s, bo_s,
              bufA, bufB, molS, n_atoms, n_bonds, stream);
    run_graph(fatoms_tgt, fbonds_tgt, agraph_tgt, bgraph_tgt, mol_idx_tgt,
              Wi16_t, Wh16_t, Wo1_t, Wo2_t, bo_t,
              bufA, bufB, molT, n_atoms, n_bonds, stream);

    diff_kernel<<<(NM * H + 255) / 256, 256, 0, stream>>>(molT, molS, dbuf, NM * H);
    // rxn_h = relu(diff @ Wrh^T + brh)   (direct-A2 mode)
    gemm_fused<<<NM / 64, 256, 0, stream>>>((const float*)nullptr, 0, 0, (const f16*)nullptr,
                                            dbuf, (const int*)nullptr, Wrh16,
                                            brh, rxn, NM);
    final_dot<<<NM, 256, 0, stream>>>(rxn, Wro, bro, (float*)d_out);
}